// Round 1
// 7070.758 us; speedup vs baseline: 1.1124x; 1.1124x over previous
//
#include <hip/hip_runtime.h>
#include <hip/hip_bf16.h>
#include <stdint.h>

// ---------------------------------------------------------------------------
// QLSTM: 2-layer LSTM, T=512, B=64, D=512, H=1024, fp32 in/out.
// R3: distributed-flag group barrier replaces the single contended atomic
// counter. Each block posts a monotone per-block phase flag (no RMW, no
// shared line); wave 0 polls all 128 flags of its batch-half group with ONE
// lane-parallel 8B load (64 lanes x 2 flags) + __all. All cross-block
// dataflow is confined to the same batch-half (mh), so the two 128-block
// groups synchronize independently. `out` stores are issued between flag
// post and poll so their write-ack drains during the wait.
// Weights persist in VGPRs; h exchanged via agent-scope relaxed load/store.
// ---------------------------------------------------------------------------

#define T_STEPS 512
#define BATCH   64
#define DIN     512
#define HID     1024
#define NBLK    256
#define NTHR    512

typedef __attribute__((ext_vector_type(8)))  short short8;   // 8 bf16
typedef __attribute__((ext_vector_type(16))) float f32x16;   // 32x32 acc

union U16 { unsigned long long u[2]; short8 v; };

// ---- workspace layout (bytes) ----
#define OFF_WIH0 ((size_t)0)          // 4 MB  bf16 [4096][512]
#define OFF_WHH0 ((size_t)4194304)    // 8 MB  bf16 [4096][1024]
#define OFF_WIH1 ((size_t)12582912)   // 8 MB
#define OFF_WHH1 ((size_t)20971520)   // 8 MB
#define OFF_XBF  ((size_t)29360128)   // 33.55 MB bf16 [512][64][512]
#define OFF_H0   ((size_t)62914560)   // 2 x 128 KB  bf16 [64][1024] per parity
#define OFF_H1   ((size_t)(OFF_H0 + 262144))
#define OFF_FLG  ((size_t)(OFF_H1 + 262144))   // 256 x u32 phase flags

// ---------------------------------------------------------------------------
__global__ void cvt_bf16x4(const float4* __restrict__ in,
                           ushort4* __restrict__ out, int n4) {
  int i = blockIdx.x * blockDim.x + threadIdx.x;
  if (i >= n4) return;
  float4 v = in[i];
  __hip_bfloat16 b0 = __float2bfloat16(v.x), b1 = __float2bfloat16(v.y),
                 b2 = __float2bfloat16(v.z), b3 = __float2bfloat16(v.w);
  ushort4 o;
  o.x = *(unsigned short*)&b0; o.y = *(unsigned short*)&b1;
  o.z = *(unsigned short*)&b2; o.w = *(unsigned short*)&b3;
  out[i] = o;
}

__device__ __forceinline__ float sigf(float x) {
  return 1.0f / (1.0f + __expf(-x));
}
__device__ __forceinline__ float tanhfast(float x) {
  // 1 - 2/(e^{2x}+1): exact at +/-inf, ~1e-6 abs err, far below bf16 quant.
  return 1.0f - 2.0f / (__expf(2.0f * x) + 1.0f);
}

// ---------------------------------------------------------------------------
__launch_bounds__(NTHR, 2)
__global__ void lstm_persist(const __hip_bfloat16* __restrict__ whh0,
                             const __hip_bfloat16* __restrict__ wih0,
                             const __hip_bfloat16* __restrict__ wih1,
                             const __hip_bfloat16* __restrict__ whh1,
                             const __hip_bfloat16* __restrict__ xbf,
                             __hip_bfloat16* h0buf, __hip_bfloat16* h1buf,
                             const float* __restrict__ bih0, const float* __restrict__ bhh0,
                             const float* __restrict__ bih1, const float* __restrict__ bhh1,
                             float* __restrict__ out, unsigned* flags) {
  __shared__ float dump[8][2][32][32];   // 64 KiB: 8 wave-partials x 2 tiles

  const int tid = threadIdx.x;
  const int w   = tid >> 6;        // wave 0..7 (K-split)
  const int l   = tid & 63;
  const int cu  = blockIdx.x;
  const bool L1cu = (cu >= 128);
  const int q  = L1cu ? (cu - 128) : cu;
  const int jt = q >> 1;           // 16-hidden-col granule
  const int mh = q & 1;            // 32-row batch half

  // flag index: group-major layout [mh][layer*64 + jt]
  const int fidx = mh * 128 + (L1cu ? 64 : 0) + jt;

  const int n    = l & 31;         // MFMA col (B) / row (A) within tile
  const int ksub = (l >> 5) * 8;   // A/B fragment k sub-offset
  const int m    = mh * 32 + n;    // batch row for A loads

  // elementwise identity
  const int erow = tid >> 4;           // 0..31
  const int ehc  = tid & 15;           // 0..15
  const int ecol = jt * 16 + ehc;
  const int em   = mh * 32 + erow;

  float bi, bf_, bg, bo;
  {
    const float* ba = L1cu ? bih1 : bih0;
    const float* bb = L1cu ? bhh1 : bhh0;
    bi  = ba[0 * HID + ecol] + bb[0 * HID + ecol];
    bf_ = ba[1 * HID + ecol] + bb[1 * HID + ecol];
    bg  = ba[2 * HID + ecol] + bb[2 * HID + ecol];
    bo  = ba[3 * HID + ecol] + bb[3 * HID + ecol];
  }
  float cst = 0.0f;

  // ---- one-time weight preload into registers ----
  const int wr0 = ((n >> 4) + 0) * HID + jt * 16 + (n & 15);
  const int wr1 = ((n >> 4) + 2) * HID + jt * 16 + (n & 15);

  short8 w1a[8], w1b[8];   // matmul1 (K=1024): L0=Whh0, L1=Wih1
  short8 w2a[8], w2b[8];   // matmul2: L0=Wih0 (K=512, 4 used), L1=Whh1 (K=1024)
  if (!L1cu) {
#pragma unroll
    for (int kk = 0; kk < 8; ++kk) {
      int k0 = (w + 8 * kk) * 16 + ksub;
      w1a[kk] = *(const short8*)(whh0 + (size_t)wr0 * 1024 + k0);
      w1b[kk] = *(const short8*)(whh0 + (size_t)wr1 * 1024 + k0);
    }
#pragma unroll
    for (int kk = 0; kk < 4; ++kk) {
      int k0 = (w + 8 * kk) * 16 + ksub;
      w2a[kk] = *(const short8*)(wih0 + (size_t)wr0 * 512 + k0);
      w2b[kk] = *(const short8*)(wih0 + (size_t)wr1 * 512 + k0);
    }
  } else {
#pragma unroll
    for (int kk = 0; kk < 8; ++kk) {
      int k0 = (w + 8 * kk) * 16 + ksub;
      w1a[kk] = *(const short8*)(wih1 + (size_t)wr0 * 1024 + k0);
      w1b[kk] = *(const short8*)(wih1 + (size_t)wr1 * 1024 + k0);
      w2a[kk] = *(const short8*)(whh1 + (size_t)wr0 * 1024 + k0);
      w2b[kk] = *(const short8*)(whh1 + (size_t)wr1 * 1024 + k0);
    }
  }

  for (int p = 0; p <= T_STEPS; ++p) {
    const bool active  = L1cu ? (p >= 1) : (p < T_STEPS);
    const bool notlast = (p < T_STEPS);
    float h = 0.0f;

    if (active) {
      const int pb = (p + 1) & 1;            // parity holding h0_{p-1}
      f32x16 acc0, acc1;
#pragma unroll
      for (int r = 0; r < 16; ++r) { acc0[r] = 0.0f; acc1[r] = 0.0f; }

      // ---- matmul1: h0_{p-1} @ W1^T  (agent-scope coherent loads) ----
      {
        const __hip_bfloat16* A1e =
            h0buf + (size_t)pb * 65536 + (size_t)m * 1024 + ksub;
        const unsigned long long* A1 = (const unsigned long long*)A1e;
        U16 a1[8];
#pragma unroll
        for (int kk = 0; kk < 8; ++kk) {
          const unsigned long long* pa = A1 + (size_t)(w + 8 * kk) * 4;
          a1[kk].u[0] = __hip_atomic_load(pa,     __ATOMIC_RELAXED, __HIP_MEMORY_SCOPE_AGENT);
          a1[kk].u[1] = __hip_atomic_load(pa + 1, __ATOMIC_RELAXED, __HIP_MEMORY_SCOPE_AGENT);
        }
#pragma unroll
        for (int kk = 0; kk < 8; ++kk) {
          acc0 = __builtin_amdgcn_mfma_f32_32x32x16_bf16(a1[kk].v, w1a[kk], acc0, 0, 0, 0);
          acc1 = __builtin_amdgcn_mfma_f32_32x32x16_bf16(a1[kk].v, w1b[kk], acc1, 0, 0, 0);
        }
      }

      // ---- matmul2 ----
      if (!L1cu) {
        // x_p @ Wih0^T : x is read-only input, normal cached loads
        const short8* A2 =
            (const short8*)(xbf + ((size_t)p * 64 + m) * 512 + ksub);
        short8 a2[4];
#pragma unroll
        for (int kk = 0; kk < 4; ++kk) a2[kk] = A2[(w + 8 * kk) * 2];
#pragma unroll
        for (int kk = 0; kk < 4; ++kk) {
          acc0 = __builtin_amdgcn_mfma_f32_32x32x16_bf16(a2[kk], w2a[kk], acc0, 0, 0, 0);
          acc1 = __builtin_amdgcn_mfma_f32_32x32x16_bf16(a2[kk], w2b[kk], acc1, 0, 0, 0);
        }
      } else {
        // h1_{p-2} @ Whh1^T : agent-scope coherent loads
        const __hip_bfloat16* A2e =
            h1buf + (size_t)(p & 1) * 65536 + (size_t)m * 1024 + ksub;
        const unsigned long long* A2 = (const unsigned long long*)A2e;
        U16 a2[8];
#pragma unroll
        for (int kk = 0; kk < 8; ++kk) {
          const unsigned long long* pa = A2 + (size_t)(w + 8 * kk) * 4;
          a2[kk].u[0] = __hip_atomic_load(pa,     __ATOMIC_RELAXED, __HIP_MEMORY_SCOPE_AGENT);
          a2[kk].u[1] = __hip_atomic_load(pa + 1, __ATOMIC_RELAXED, __HIP_MEMORY_SCOPE_AGENT);
        }
#pragma unroll
        for (int kk = 0; kk < 8; ++kk) {
          acc0 = __builtin_amdgcn_mfma_f32_32x32x16_bf16(a2[kk].v, w2a[kk], acc0, 0, 0, 0);
          acc1 = __builtin_amdgcn_mfma_f32_32x32x16_bf16(a2[kk].v, w2b[kk], acc1, 0, 0, 0);
        }
      }

      // ---- dump wave partials (C/D: col=lane&31, row=(r&3)+8*(r>>2)+4*(lane>>5))
      __syncthreads();
#pragma unroll
      for (int r = 0; r < 16; ++r) {
        int row = (r & 3) + 8 * (r >> 2) + 4 * (l >> 5);
        dump[w][0][row][n] = acc0[r];
        dump[w][1][row][n] = acc1[r];
      }
      __syncthreads();

      // ---- reduce 8 partials + LSTM cell ----
      float gi = bi, gf = bf_, gg = bg, go = bo;
#pragma unroll
      for (int ww = 0; ww < 8; ++ww) {
        gi += dump[ww][0][erow][ehc];
        gf += dump[ww][0][erow][ehc + 16];
        gg += dump[ww][1][erow][ehc];
        go += dump[ww][1][erow][ehc + 16];
      }
      float si = sigf(gi), sf = sigf(gf), so = sigf(go);
      float tg = tanhfast(gg);
      cst = sf * cst + si * tg;
      h = so * tanhfast(cst);

      // ---- coherent h write: pair lanes -> one 4B agent-scope store ----
      if (notlast) {
        __hip_bfloat16 hbf = __float2bfloat16(h);
        unsigned hb = *(const unsigned short*)&hbf;
        unsigned pr = __shfl_xor(hb, 1);
        __hip_bfloat16* hdst = L1cu ? (h1buf + (size_t)((p + 1) & 1) * 65536)
                                    : (h0buf + (size_t)(p & 1) * 65536);
        if ((ehc & 1) == 0) {
          unsigned pv = hb | (pr << 16);
          __hip_atomic_store((unsigned*)(hdst + (size_t)em * 1024 + ecol), pv,
                             __ATOMIC_RELAXED, __HIP_MEMORY_SCOPE_AGENT);
        }
      }
    }

    // ---- post phase-completion flag (h stores drained first) ----
    if (notlast) {
      asm volatile("s_waitcnt vmcnt(0)" ::: "memory");
      __syncthreads();
      if (tid == 0)
        __hip_atomic_store(flags + fidx, (unsigned)(p + 1),
                           __ATOMIC_RELAXED, __HIP_MEMORY_SCOPE_AGENT);
    }

    // ---- out stores issued in the flag->poll window (drain overlaps poll) ----
    if (active) {
      if (!L1cu) {
        if (p == T_STEPS - 1) {   // final h0, c0
          out[(size_t)T_STEPS * BATCH * HID + 0 * BATCH * HID + (size_t)em * HID + ecol] = h;
          out[(size_t)T_STEPS * BATCH * HID + 1 * BATCH * HID + (size_t)em * HID + ecol] = cst;
        }
      } else {
        out[((size_t)(p - 1) * BATCH + em) * HID + ecol] = h;   // sequence out
        if (p == T_STEPS) {       // final h1, c1
          out[(size_t)T_STEPS * BATCH * HID + 2 * BATCH * HID + (size_t)em * HID + ecol] = h;
          out[(size_t)T_STEPS * BATCH * HID + 3 * BATCH * HID + (size_t)em * HID + ecol] = cst;
        }
      }
    }

    // ---- lane-parallel group barrier poll: 64 lanes x 2 flags = 128 flags ----
    if (notlast) {
      if (w == 0) {
        const unsigned tgt = (unsigned)(p + 1);
        const unsigned long long* f64 =
            (const unsigned long long*)(flags + (size_t)mh * 128) + l;
        for (;;) {
          unsigned long long v =
              __hip_atomic_load(f64, __ATOMIC_RELAXED, __HIP_MEMORY_SCOPE_AGENT);
          if (__all(((unsigned)v >= tgt) & ((unsigned)(v >> 32) >= tgt))) break;
          __builtin_amdgcn_s_sleep(1);
        }
      }
      __syncthreads();
    }
  }
}

// ---------------------------------------------------------------------------
extern "C" void kernel_launch(void* const* d_in, const int* in_sizes, int n_in,
                              void* d_out, int out_size, void* d_ws, size_t ws_size,
                              hipStream_t stream) {
  const float* x     = (const float*)d_in[0];
  const float* Wih0  = (const float*)d_in[1];
  const float* Whh0  = (const float*)d_in[2];
  const float* b_ih0 = (const float*)d_in[3];
  const float* b_hh0 = (const float*)d_in[4];
  const float* Wih1  = (const float*)d_in[5];
  const float* Whh1  = (const float*)d_in[6];
  const float* b_ih1 = (const float*)d_in[7];
  const float* b_hh1 = (const float*)d_in[8];
  float* out = (float*)d_out;

  char* ws = (char*)d_ws;
  __hip_bfloat16* wih0p = (__hip_bfloat16*)(ws + OFF_WIH0);
  __hip_bfloat16* whh0p = (__hip_bfloat16*)(ws + OFF_WHH0);
  __hip_bfloat16* wih1p = (__hip_bfloat16*)(ws + OFF_WIH1);
  __hip_bfloat16* whh1p = (__hip_bfloat16*)(ws + OFF_WHH1);
  __hip_bfloat16* xbfp  = (__hip_bfloat16*)(ws + OFF_XBF);
  __hip_bfloat16* h0p   = (__hip_bfloat16*)(ws + OFF_H0);
  __hip_bfloat16* h1p   = (__hip_bfloat16*)(ws + OFF_H1);
  unsigned* flg         = (unsigned*)(ws + OFF_FLG);

  // zero h double-buffers + 256 phase flags (ws re-poisoned each call)
  hipMemsetAsync(ws + OFF_H0, 0, 262144 * 2 + 1024, stream);

  // fp32 -> bf16 plain row-major copies
  cvt_bf16x4<<<2048,  256, 0, stream>>>((const float4*)Wih0, (ushort4*)wih0p, 2097152 / 4);
  cvt_bf16x4<<<4096,  256, 0, stream>>>((const float4*)Whh0, (ushort4*)whh0p, 4194304 / 4);
  cvt_bf16x4<<<4096,  256, 0, stream>>>((const float4*)Wih1, (ushort4*)wih1p, 4194304 / 4);
  cvt_bf16x4<<<4096,  256, 0, stream>>>((const float4*)Whh1, (ushort4*)whh1p, 4194304 / 4);
  cvt_bf16x4<<<16384, 256, 0, stream>>>((const float4*)x,    (ushort4*)xbfp, 16777216 / 4);

  void* args[] = { &whh0p, &wih0p, &wih1p, &whh1p, &xbfp, &h0p, &h1p,
                   (void*)&b_ih0, (void*)&b_hh0, (void*)&b_ih1, (void*)&b_hh1,
                   &out, &flg };
  hipLaunchCooperativeKernel((const void*)lstm_persist, dim3(NBLK), dim3(NTHR),
                             args, 0, stream);
}

// Round 2
// 6270.126 us; speedup vs baseline: 1.2544x; 1.1277x over previous
//
#include <hip/hip_runtime.h>
#include <hip/hip_bf16.h>
#include <stdint.h>

// ---------------------------------------------------------------------------
// QLSTM: 2-layer LSTM, T=512, B=64, D=512, H=1024, fp32 in/out.
// R4: h broadcast reads become CACHED loads (L2-shared per XCD, ~1 MB/phase
// fetched) instead of agent-scope uncached loads (24 MB/phase from MALL).
// Coherence: producers keep sc1 write-through h stores (drained before flag
// post); consumers, after the flag poll succeeds, invalidate L1+L2
// (s_waitcnt vmcnt(0); buffer_inv sc1 + acquire fence) so the cached loads
// re-fetch fresh lines once per XCD (MSHR-coalesced across the 32 blocks
// sharing the same mh-half on that XCD). `out` stores are write-through
// (agent scope) so the kernel never holds dirty L2 lines across buffer_inv.
// Everything else (flags barrier, tiling, LDS reduce) unchanged from R3.
// ---------------------------------------------------------------------------

#define T_STEPS 512
#define BATCH   64
#define DIN     512
#define HID     1024
#define NBLK    256
#define NTHR    512

typedef __attribute__((ext_vector_type(8)))  short short8;   // 8 bf16
typedef __attribute__((ext_vector_type(16))) float f32x16;   // 32x32 acc

// ---- workspace layout (bytes) ----
#define OFF_WIH0 ((size_t)0)          // 4 MB  bf16 [4096][512]
#define OFF_WHH0 ((size_t)4194304)    // 8 MB  bf16 [4096][1024]
#define OFF_WIH1 ((size_t)12582912)   // 8 MB
#define OFF_WHH1 ((size_t)20971520)   // 8 MB
#define OFF_XBF  ((size_t)29360128)   // 33.55 MB bf16 [512][64][512]
#define OFF_H0   ((size_t)62914560)   // 2 x 128 KB  bf16 [64][1024] per parity
#define OFF_H1   ((size_t)(OFF_H0 + 262144))
#define OFF_FLG  ((size_t)(OFF_H1 + 262144))   // 256 x u32 phase flags

// ---------------------------------------------------------------------------
__global__ void cvt_bf16x4(const float4* __restrict__ in,
                           ushort4* __restrict__ out, int n4) {
  int i = blockIdx.x * blockDim.x + threadIdx.x;
  if (i >= n4) return;
  float4 v = in[i];
  __hip_bfloat16 b0 = __float2bfloat16(v.x), b1 = __float2bfloat16(v.y),
                 b2 = __float2bfloat16(v.z), b3 = __float2bfloat16(v.w);
  ushort4 o;
  o.x = *(unsigned short*)&b0; o.y = *(unsigned short*)&b1;
  o.z = *(unsigned short*)&b2; o.w = *(unsigned short*)&b3;
  out[i] = o;
}

__device__ __forceinline__ float sigf(float x) {
  return 1.0f / (1.0f + __expf(-x));
}
__device__ __forceinline__ float tanhfast(float x) {
  // 1 - 2/(e^{2x}+1): exact at +/-inf, ~1e-6 abs err, far below bf16 quant.
  return 1.0f - 2.0f / (__expf(2.0f * x) + 1.0f);
}

// ---------------------------------------------------------------------------
__launch_bounds__(NTHR, 2)
__global__ void lstm_persist(const __hip_bfloat16* __restrict__ whh0,
                             const __hip_bfloat16* __restrict__ wih0,
                             const __hip_bfloat16* __restrict__ wih1,
                             const __hip_bfloat16* __restrict__ whh1,
                             const __hip_bfloat16* __restrict__ xbf,
                             __hip_bfloat16* h0buf, __hip_bfloat16* h1buf,
                             const float* __restrict__ bih0, const float* __restrict__ bhh0,
                             const float* __restrict__ bih1, const float* __restrict__ bhh1,
                             float* __restrict__ out, unsigned* flags) {
  __shared__ float dump[8][2][32][32];   // 64 KiB: 8 wave-partials x 2 tiles

  const int tid = threadIdx.x;
  const int w   = tid >> 6;        // wave 0..7 (K-split)
  const int l   = tid & 63;
  const int cu  = blockIdx.x;
  const bool L1cu = (cu >= 128);
  const int q  = L1cu ? (cu - 128) : cu;
  const int jt = q >> 1;           // 16-hidden-col granule
  const int mh = q & 1;            // 32-row batch half

  // flag index: group-major layout [mh][layer*64 + jt]
  const int fidx = mh * 128 + (L1cu ? 64 : 0) + jt;

  const int n    = l & 31;         // MFMA col (B) / row (A) within tile
  const int ksub = (l >> 5) * 8;   // A/B fragment k sub-offset
  const int m    = mh * 32 + n;    // batch row for A loads

  // elementwise identity
  const int erow = tid >> 4;           // 0..31
  const int ehc  = tid & 15;           // 0..15
  const int ecol = jt * 16 + ehc;
  const int em   = mh * 32 + erow;

  float bi, bf_, bg, bo;
  {
    const float* ba = L1cu ? bih1 : bih0;
    const float* bb = L1cu ? bhh1 : bhh0;
    bi  = ba[0 * HID + ecol] + bb[0 * HID + ecol];
    bf_ = ba[1 * HID + ecol] + bb[1 * HID + ecol];
    bg  = ba[2 * HID + ecol] + bb[2 * HID + ecol];
    bo  = ba[3 * HID + ecol] + bb[3 * HID + ecol];
  }
  float cst = 0.0f;

  // ---- one-time weight preload into registers ----
  const int wr0 = ((n >> 4) + 0) * HID + jt * 16 + (n & 15);
  const int wr1 = ((n >> 4) + 2) * HID + jt * 16 + (n & 15);

  short8 w1a[8], w1b[8];   // matmul1 (K=1024): L0=Whh0, L1=Wih1
  short8 w2a[8], w2b[8];   // matmul2: L0=Wih0 (K=512, 4 used), L1=Whh1 (K=1024)
  if (!L1cu) {
#pragma unroll
    for (int kk = 0; kk < 8; ++kk) {
      int k0 = (w + 8 * kk) * 16 + ksub;
      w1a[kk] = *(const short8*)(whh0 + (size_t)wr0 * 1024 + k0);
      w1b[kk] = *(const short8*)(whh0 + (size_t)wr1 * 1024 + k0);
    }
#pragma unroll
    for (int kk = 0; kk < 4; ++kk) {
      int k0 = (w + 8 * kk) * 16 + ksub;
      w2a[kk] = *(const short8*)(wih0 + (size_t)wr0 * 512 + k0);
      w2b[kk] = *(const short8*)(wih0 + (size_t)wr1 * 512 + k0);
    }
  } else {
#pragma unroll
    for (int kk = 0; kk < 8; ++kk) {
      int k0 = (w + 8 * kk) * 16 + ksub;
      w1a[kk] = *(const short8*)(wih1 + (size_t)wr0 * 1024 + k0);
      w1b[kk] = *(const short8*)(wih1 + (size_t)wr1 * 1024 + k0);
      w2a[kk] = *(const short8*)(whh1 + (size_t)wr0 * 1024 + k0);
      w2b[kk] = *(const short8*)(whh1 + (size_t)wr1 * 1024 + k0);
    }
  }

  for (int p = 0; p <= T_STEPS; ++p) {
    const bool active  = L1cu ? (p >= 1) : (p < T_STEPS);
    const bool notlast = (p < T_STEPS);
    float h = 0.0f;

    if (active) {
      const int pb = (p + 1) & 1;            // parity holding h0_{p-1}
      f32x16 acc0, acc1;
#pragma unroll
      for (int r = 0; r < 16; ++r) { acc0[r] = 0.0f; acc1[r] = 0.0f; }

      // ---- matmul1: h0_{p-1} @ W1^T  (CACHED loads; buffer_inv ran after
      //      the flag poll, so these hit fresh lines, L2-shared per XCD) ----
      {
        const short8* A1 =
            (const short8*)(h0buf + (size_t)pb * 65536 + (size_t)m * 1024 + ksub);
        short8 a1[8];
#pragma unroll
        for (int kk = 0; kk < 8; ++kk) a1[kk] = A1[(w + 8 * kk) * 2];
#pragma unroll
        for (int kk = 0; kk < 8; ++kk) {
          acc0 = __builtin_amdgcn_mfma_f32_32x32x16_bf16(a1[kk], w1a[kk], acc0, 0, 0, 0);
          acc1 = __builtin_amdgcn_mfma_f32_32x32x16_bf16(a1[kk], w1b[kk], acc1, 0, 0, 0);
        }
      }

      // ---- matmul2 ----
      if (!L1cu) {
        // x_p @ Wih0^T : x is read-only input, normal cached loads
        const short8* A2 =
            (const short8*)(xbf + ((size_t)p * 64 + m) * 512 + ksub);
        short8 a2[4];
#pragma unroll
        for (int kk = 0; kk < 4; ++kk) a2[kk] = A2[(w + 8 * kk) * 2];
#pragma unroll
        for (int kk = 0; kk < 4; ++kk) {
          acc0 = __builtin_amdgcn_mfma_f32_32x32x16_bf16(a2[kk], w2a[kk], acc0, 0, 0, 0);
          acc1 = __builtin_amdgcn_mfma_f32_32x32x16_bf16(a2[kk], w2b[kk], acc1, 0, 0, 0);
        }
      } else {
        // h1_{p-2} @ Whh1^T : cached loads (covered by the same invalidate)
        const short8* A2 =
            (const short8*)(h1buf + (size_t)(p & 1) * 65536 + (size_t)m * 1024 + ksub);
        short8 a2[8];
#pragma unroll
        for (int kk = 0; kk < 8; ++kk) a2[kk] = A2[(w + 8 * kk) * 2];
#pragma unroll
        for (int kk = 0; kk < 8; ++kk) {
          acc0 = __builtin_amdgcn_mfma_f32_32x32x16_bf16(a2[kk], w2a[kk], acc0, 0, 0, 0);
          acc1 = __builtin_amdgcn_mfma_f32_32x32x16_bf16(a2[kk], w2b[kk], acc1, 0, 0, 0);
        }
      }

      // ---- dump wave partials (C/D: col=lane&31, row=(r&3)+8*(r>>2)+4*(lane>>5))
      __syncthreads();
#pragma unroll
      for (int r = 0; r < 16; ++r) {
        int row = (r & 3) + 8 * (r >> 2) + 4 * (l >> 5);
        dump[w][0][row][n] = acc0[r];
        dump[w][1][row][n] = acc1[r];
      }
      __syncthreads();

      // ---- reduce 8 partials + LSTM cell ----
      float gi = bi, gf = bf_, gg = bg, go = bo;
#pragma unroll
      for (int ww = 0; ww < 8; ++ww) {
        gi += dump[ww][0][erow][ehc];
        gf += dump[ww][0][erow][ehc + 16];
        gg += dump[ww][1][erow][ehc];
        go += dump[ww][1][erow][ehc + 16];
      }
      float si = sigf(gi), sf = sigf(gf), so = sigf(go);
      float tg = tanhfast(gg);
      cst = sf * cst + si * tg;
      h = so * tanhfast(cst);

      // ---- coherent h write: pair lanes -> one 4B agent-scope store ----
      if (notlast) {
        __hip_bfloat16 hbf = __float2bfloat16(h);
        unsigned hb = *(const unsigned short*)&hbf;
        unsigned pr = __shfl_xor(hb, 1);
        __hip_bfloat16* hdst = L1cu ? (h1buf + (size_t)((p + 1) & 1) * 65536)
                                    : (h0buf + (size_t)(p & 1) * 65536);
        if ((ehc & 1) == 0) {
          unsigned pv = hb | (pr << 16);
          __hip_atomic_store((unsigned*)(hdst + (size_t)em * 1024 + ecol), pv,
                             __ATOMIC_RELAXED, __HIP_MEMORY_SCOPE_AGENT);
        }
      }
    }

    // ---- post phase-completion flag (h stores drained first) ----
    if (notlast) {
      asm volatile("s_waitcnt vmcnt(0)" ::: "memory");
      __syncthreads();
      if (tid == 0)
        __hip_atomic_store(flags + fidx, (unsigned)(p + 1),
                           __ATOMIC_RELAXED, __HIP_MEMORY_SCOPE_AGENT);
    }

    // ---- out stores: WRITE-THROUGH (agent scope) so no dirty L2 lines
    //      exist when buffer_inv runs; drain overlaps the poll ----
    if (active) {
      if (!L1cu) {
        if (p == T_STEPS - 1) {   // final h0, c0
          __hip_atomic_store(
              &out[(size_t)T_STEPS * BATCH * HID + 0 * BATCH * HID + (size_t)em * HID + ecol],
              h, __ATOMIC_RELAXED, __HIP_MEMORY_SCOPE_AGENT);
          __hip_atomic_store(
              &out[(size_t)T_STEPS * BATCH * HID + 1 * BATCH * HID + (size_t)em * HID + ecol],
              cst, __ATOMIC_RELAXED, __HIP_MEMORY_SCOPE_AGENT);
        }
      } else {
        __hip_atomic_store(&out[((size_t)(p - 1) * BATCH + em) * HID + ecol],
                           h, __ATOMIC_RELAXED, __HIP_MEMORY_SCOPE_AGENT);
        if (p == T_STEPS) {       // final h1, c1
          __hip_atomic_store(
              &out[(size_t)T_STEPS * BATCH * HID + 2 * BATCH * HID + (size_t)em * HID + ecol],
              h, __ATOMIC_RELAXED, __HIP_MEMORY_SCOPE_AGENT);
          __hip_atomic_store(
              &out[(size_t)T_STEPS * BATCH * HID + 3 * BATCH * HID + (size_t)em * HID + ecol],
              cst, __ATOMIC_RELAXED, __HIP_MEMORY_SCOPE_AGENT);
        }
      }
    }

    // ---- lane-parallel group barrier poll: 64 lanes x 2 flags = 128 flags ----
    if (notlast) {
      if (w == 0) {
        const unsigned tgt = (unsigned)(p + 1);
        const unsigned long long* f64 =
            (const unsigned long long*)(flags + (size_t)mh * 128) + l;
        for (;;) {
          unsigned long long v =
              __hip_atomic_load(f64, __ATOMIC_RELAXED, __HIP_MEMORY_SCOPE_AGENT);
          if (__all(((unsigned)v >= tgt) & ((unsigned)(v >> 32) >= tgt))) break;
          __builtin_amdgcn_s_sleep(1);
        }
        // Make remote sc1 h-stores visible to subsequent CACHED loads:
        // drain our own loads, then invalidate L1 + this XCD's L2.
        asm volatile("s_waitcnt vmcnt(0)\n\tbuffer_inv sc1" ::: "memory");
        __builtin_amdgcn_fence(__ATOMIC_ACQUIRE, "agent");
      }
      __syncthreads();   // orders other waves' h loads after the invalidate
    }
  }
}

// ---------------------------------------------------------------------------
extern "C" void kernel_launch(void* const* d_in, const int* in_sizes, int n_in,
                              void* d_out, int out_size, void* d_ws, size_t ws_size,
                              hipStream_t stream) {
  const float* x     = (const float*)d_in[0];
  const float* Wih0  = (const float*)d_in[1];
  const float* Whh0  = (const float*)d_in[2];
  const float* b_ih0 = (const float*)d_in[3];
  const float* b_hh0 = (const float*)d_in[4];
  const float* Wih1  = (const float*)d_in[5];
  const float* Whh1  = (const float*)d_in[6];
  const float* b_ih1 = (const float*)d_in[7];
  const float* b_hh1 = (const float*)d_in[8];
  float* out = (float*)d_out;

  char* ws = (char*)d_ws;
  __hip_bfloat16* wih0p = (__hip_bfloat16*)(ws + OFF_WIH0);
  __hip_bfloat16* whh0p = (__hip_bfloat16*)(ws + OFF_WHH0);
  __hip_bfloat16* wih1p = (__hip_bfloat16*)(ws + OFF_WIH1);
  __hip_bfloat16* whh1p = (__hip_bfloat16*)(ws + OFF_WHH1);
  __hip_bfloat16* xbfp  = (__hip_bfloat16*)(ws + OFF_XBF);
  __hip_bfloat16* h0p   = (__hip_bfloat16*)(ws + OFF_H0);
  __hip_bfloat16* h1p   = (__hip_bfloat16*)(ws + OFF_H1);
  unsigned* flg         = (unsigned*)(ws + OFF_FLG);

  // zero h double-buffers + 256 phase flags (ws re-poisoned each call)
  hipMemsetAsync(ws + OFF_H0, 0, 262144 * 2 + 1024, stream);

  // fp32 -> bf16 plain row-major copies
  cvt_bf16x4<<<2048,  256, 0, stream>>>((const float4*)Wih0, (ushort4*)wih0p, 2097152 / 4);
  cvt_bf16x4<<<4096,  256, 0, stream>>>((const float4*)Whh0, (ushort4*)whh0p, 4194304 / 4);
  cvt_bf16x4<<<4096,  256, 0, stream>>>((const float4*)Wih1, (ushort4*)wih1p, 4194304 / 4);
  cvt_bf16x4<<<4096,  256, 0, stream>>>((const float4*)Whh1, (ushort4*)whh1p, 4194304 / 4);
  cvt_bf16x4<<<16384, 256, 0, stream>>>((const float4*)x,    (ushort4*)xbfp, 16777216 / 4);

  void* args[] = { &whh0p, &wih0p, &wih1p, &whh1p, &xbfp, &h0p, &h1p,
                   (void*)&b_ih0, (void*)&b_hh0, (void*)&b_ih1, (void*)&b_hh1,
                   &out, &flg };
  hipLaunchCooperativeKernel((const void*)lstm_persist, dim3(NBLK), dim3(NTHR),
                             args, 0, stream);
}